// Round 1
// baseline (1182.751 us; speedup 1.0000x reference)
//
#include <hip/hip_runtime.h>
#include <math.h>

// Problem constants (from reference: B=2, L=2048, D=1024, H=16, FACTOR=5)
#define B_ 2
#define L_ 2048
#define D_ 1024
#define H_ 16
#define DH_ 64
#define U_ 40          // min(5 * ceil(ln(2048)) , 2048) = 5*8 = 40
#define SCALE_ 0.125f  // 1/sqrt(64)

#define BM 64
#define BN 64
#define BK 16

// ---------------------------------------------------------------------------
// Generic f32 GEMM: Y[M][N] = X[M][Kd] @ W[N][Kd]^T + bias[N]
// 256 threads, 64x64 tile, 4x4 per thread.
// ---------------------------------------------------------------------------
__global__ __launch_bounds__(256) void gemm_xwT(
    const float* __restrict__ X, const float* __restrict__ W,
    const float* __restrict__ bias, float* __restrict__ Y,
    int M, int N, int Kd) {
  __shared__ float As[BM][BK + 1];
  __shared__ float Bs[BK][BN + 1];
  const int tid = threadIdx.x;
  const int tx = tid & 15, ty = tid >> 4;
  const int row0 = blockIdx.y * BM, col0 = blockIdx.x * BN;
  float acc[4][4] = {};
  for (int k0 = 0; k0 < Kd; k0 += BK) {
#pragma unroll
    for (int i = 0; i < 4; ++i)
      As[ty + 16 * i][tx] = X[(size_t)(row0 + ty + 16 * i) * Kd + k0 + tx];
#pragma unroll
    for (int i = 0; i < 4; ++i)
      Bs[tx][ty + 16 * i] = W[(size_t)(col0 + ty + 16 * i) * Kd + k0 + tx];
    __syncthreads();
#pragma unroll
    for (int kk = 0; kk < BK; ++kk) {
      float a[4], b[4];
#pragma unroll
      for (int i = 0; i < 4; ++i) a[i] = As[ty * 4 + i][kk];
#pragma unroll
      for (int j = 0; j < 4; ++j) b[j] = Bs[kk][tx * 4 + j];
#pragma unroll
      for (int i = 0; i < 4; ++i)
#pragma unroll
        for (int j = 0; j < 4; ++j) acc[i][j] += a[i] * b[j];
    }
    __syncthreads();
  }
#pragma unroll
  for (int i = 0; i < 4; ++i) {
    int r = row0 + ty * 4 + i;
#pragma unroll
    for (int j = 0; j < 4; ++j) {
      int c = col0 + tx * 4 + j;
      Y[(size_t)r * N + c] = acc[i][j] + bias[c];
    }
  }
}

// ---------------------------------------------------------------------------
// Fused QKV GEMM: rows = (b,l) of x, cols n in [0,3072):
//   n <  1024 -> Q col n       (weights Wq,  bias bq)
//   n >= 1024 -> KV col n-1024 (weights Wkv, bias bkv); first 1024 = K, next = V
// Output written directly in (b, h, l, dh) layout for Q, K, V.
// ---------------------------------------------------------------------------
__global__ __launch_bounds__(256) void gemm_qkv(
    const float* __restrict__ X,
    const float* __restrict__ Wq, const float* __restrict__ bq,
    const float* __restrict__ Wkv, const float* __restrict__ bkv,
    float* __restrict__ Q, float* __restrict__ Kt, float* __restrict__ Vt) {
  __shared__ float As[BM][BK + 1];
  __shared__ float Bs[BK][BN + 1];
  const int tid = threadIdx.x;
  const int tx = tid & 15, ty = tid >> 4;
  const int row0 = blockIdx.y * BM, col0 = blockIdx.x * BN;
  float acc[4][4] = {};
  for (int k0 = 0; k0 < D_; k0 += BK) {
#pragma unroll
    for (int i = 0; i < 4; ++i)
      As[ty + 16 * i][tx] = X[(size_t)(row0 + ty + 16 * i) * D_ + k0 + tx];
#pragma unroll
    for (int i = 0; i < 4; ++i) {
      int n = col0 + ty + 16 * i;
      const float* wr = (n < D_) ? (Wq + (size_t)n * D_)
                                 : (Wkv + (size_t)(n - D_) * D_);
      Bs[tx][ty + 16 * i] = wr[k0 + tx];
    }
    __syncthreads();
#pragma unroll
    for (int kk = 0; kk < BK; ++kk) {
      float a[4], b[4];
#pragma unroll
      for (int i = 0; i < 4; ++i) a[i] = As[ty * 4 + i][kk];
#pragma unroll
      for (int j = 0; j < 4; ++j) b[j] = Bs[kk][tx * 4 + j];
#pragma unroll
      for (int i = 0; i < 4; ++i)
#pragma unroll
        for (int j = 0; j < 4; ++j) acc[i][j] += a[i] * b[j];
    }
    __syncthreads();
  }
#pragma unroll
  for (int i = 0; i < 4; ++i) {
    int r = row0 + ty * 4 + i;
    int b = r >> 11, l = r & (L_ - 1);
#pragma unroll
    for (int j = 0; j < 4; ++j) {
      int c = col0 + tx * 4 + j;
      int which = c >> 10;          // 0=Q 1=K 2=V
      int jj = c & (D_ - 1);
      int h = jj >> 6, dh = jj & 63;
      float bias = (c < D_) ? bq[c] : bkv[c - D_];
      float val = acc[i][j] + bias;
      float* dst = (which == 0) ? Q : ((which == 1) ? Kt : Vt);
      dst[(((size_t)b * H_ + h) * L_ + l) * DH_ + dh] = val;
    }
  }
}

// ---------------------------------------------------------------------------
// M[b,h,l] = max_u(QK) - mean_u(QK), QK_u = Q[b,h,l,:] . K[b,h,idx[l,u],:]
// One 64-thread block per (b*h, l).
// ---------------------------------------------------------------------------
__global__ __launch_bounds__(64) void sample_m(
    const float* __restrict__ Q, const float* __restrict__ Kt,
    const int* __restrict__ idx, float* __restrict__ Mv) {
  int gl = blockIdx.x;           // bh * L + l
  int bh = gl >> 11, l = gl & (L_ - 1);
  __shared__ float qs[DH_];
  __shared__ float dots[U_];
  int t = threadIdx.x;
  qs[t] = Q[((size_t)bh * L_ + l) * DH_ + t];
  __syncthreads();
  if (t < U_) {
    int kl = idx[l * U_ + t];
    const float* kr = Kt + ((size_t)bh * L_ + kl) * DH_;
    float d = 0.f;
#pragma unroll
    for (int i = 0; i < DH_; ++i) d += qs[i] * kr[i];
    dots[t] = d;
  }
  __syncthreads();
  if (t == 0) {
    float mx = dots[0], sm = 0.f;
    for (int u = 0; u < U_; ++u) { mx = fmaxf(mx, dots[u]); sm += dots[u]; }
    Mv[gl] = mx - sm * (1.0f / U_);
  }
}

// ---------------------------------------------------------------------------
// Per-(b,h): indices of the U_ largest M values (min-index tie-break, which
// matches jax.lax.top_k's selected SET; order is irrelevant downstream).
// ---------------------------------------------------------------------------
__global__ __launch_bounds__(256) void topk_kernel(
    const float* __restrict__ Mv, int* __restrict__ topIdx) {
  int bh = blockIdx.x;
  __shared__ float vals[L_];
  __shared__ float rv[256];
  __shared__ int ri[256];
  int t = threadIdx.x;
  for (int i = t; i < L_; i += 256) vals[i] = Mv[(size_t)bh * L_ + i];
  __syncthreads();
  for (int it = 0; it < U_; ++it) {
    float bv = -INFINITY; int bi = 0x7fffffff;
    for (int i = t; i < L_; i += 256) {
      float v = vals[i];
      if (v > bv) { bv = v; bi = i; }
    }
    rv[t] = bv; ri[t] = bi;
    __syncthreads();
    for (int s = 128; s > 0; s >>= 1) {
      if (t < s) {
        float ov = rv[t + s]; int oi = ri[t + s];
        if (ov > rv[t] || (ov == rv[t] && oi < ri[t])) { rv[t] = ov; ri[t] = oi; }
      }
      __syncthreads();
    }
    if (t == 0) { topIdx[bh * U_ + it] = ri[0]; vals[ri[0]] = -INFINITY; }
    __syncthreads();
  }
}

// ---------------------------------------------------------------------------
// Full attention for each selected query: one 256-thread block per (b,h,u).
// ---------------------------------------------------------------------------
__global__ __launch_bounds__(256) void attn_topq(
    const float* __restrict__ Q, const float* __restrict__ Kt,
    const float* __restrict__ Vt, const int* __restrict__ topIdx,
    float* __restrict__ ctxUpd) {
  int bh = blockIdx.x / U_;
  int u  = blockIdx.x % U_;
  int ql = topIdx[bh * U_ + u];
  __shared__ float qs[DH_];
  __shared__ float sc[L_];
  __shared__ float red[256];
  int t = threadIdx.x;
  if (t < DH_) qs[t] = Q[((size_t)bh * L_ + ql) * DH_ + t];
  __syncthreads();
  float lmax = -INFINITY;
  for (int k = t; k < L_; k += 256) {
    const float* kr = Kt + ((size_t)bh * L_ + k) * DH_;
    float d = 0.f;
#pragma unroll
    for (int i = 0; i < DH_; ++i) d += qs[i] * kr[i];
    d *= SCALE_;
    sc[k] = d;
    lmax = fmaxf(lmax, d);
  }
  red[t] = lmax; __syncthreads();
  for (int s = 128; s > 0; s >>= 1) {
    if (t < s) red[t] = fmaxf(red[t], red[t + s]);
    __syncthreads();
  }
  float mx = red[0];
  __syncthreads();
  float lsum = 0.f;
  for (int k = t; k < L_; k += 256) {
    float e = expf(sc[k] - mx);
    sc[k] = e;
    lsum += e;
  }
  red[t] = lsum; __syncthreads();
  for (int s = 128; s > 0; s >>= 1) {
    if (t < s) red[t] += red[t + s];
    __syncthreads();
  }
  float inv = 1.0f / red[0];
  __syncthreads();
  int dh = t & 63, ch = t >> 6;   // 4 key-chunks of 512
  float acc = 0.f;
  for (int k = ch * (L_ / 4); k < (ch + 1) * (L_ / 4); ++k)
    acc += sc[k] * Vt[((size_t)bh * L_ + k) * DH_ + dh];
  red[t] = acc; __syncthreads();
  if (ch == 0) {
    float r = (red[dh] + red[dh + 64]) + (red[dh + 128] + red[dh + 192]);
    ctxUpd[((size_t)bh * U_ + u) * DH_ + dh] = r * inv;
  }
}

// ---------------------------------------------------------------------------
// vmean[b,h,dh] = mean over l of V
// ---------------------------------------------------------------------------
__global__ __launch_bounds__(256) void vmean_kernel(
    const float* __restrict__ Vt, float* __restrict__ vmean) {
  int bh = blockIdx.x;
  int t = threadIdx.x;
  int dh = t & 63, ch = t >> 6;
  __shared__ float red[256];
  float s = 0.f;
  for (int l = ch * (L_ / 4); l < (ch + 1) * (L_ / 4); ++l)
    s += Vt[((size_t)bh * L_ + l) * DH_ + dh];
  red[t] = s; __syncthreads();
  if (ch == 0)
    vmean[bh * DH_ + dh] =
        ((red[dh] + red[dh + 64]) + (red[dh + 128] + red[dh + 192])) *
        (1.0f / L_);
}

// ---------------------------------------------------------------------------
// context[b][l][h*64+dh] = vmean[b,h,dh]  (broadcast fill)
// ---------------------------------------------------------------------------
__global__ __launch_bounds__(256) void fill_context(
    const float* __restrict__ vmean, float* __restrict__ ctx) {
  size_t i = (size_t)blockIdx.x * 256 + threadIdx.x;  // over B*L*D
  int j = (int)(i & (D_ - 1));
  size_t bl = i >> 10;
  int b = (int)(bl >> 11);
  int h = j >> 6, dh = j & 63;
  ctx[i] = vmean[((b * H_ + h) << 6) + dh];
}

// ---------------------------------------------------------------------------
// Scatter ctx_update rows into context at the selected query positions.
// ---------------------------------------------------------------------------
__global__ __launch_bounds__(64) void scatter_ctx(
    const int* __restrict__ topIdx, const float* __restrict__ ctxUpd,
    float* __restrict__ ctx) {
  int bhu = blockIdx.x;
  int bh = bhu / U_;
  int b = bh / H_, h = bh % H_;
  int l = topIdx[bhu];
  ctx[((size_t)b * L_ + l) * D_ + h * DH_ + threadIdx.x] =
      ctxUpd[(size_t)bhu * DH_ + threadIdx.x];
}

// ---------------------------------------------------------------------------
extern "C" void kernel_launch(void* const* d_in, const int* in_sizes, int n_in,
                              void* d_out, int out_size, void* d_ws,
                              size_t ws_size, hipStream_t stream) {
  const float* x    = (const float*)d_in[0];
  const float* Wq   = (const float*)d_in[1];
  const float* bq   = (const float*)d_in[2];
  const float* Wkv  = (const float*)d_in[3];
  const float* bkv  = (const float*)d_in[4];
  const float* Wout = (const float*)d_in[5];
  const float* bout = (const float*)d_in[6];
  const int*   idx  = (const int*)d_in[7];
  // d_in[8] = factor (always 5 for this problem; U_ hard-coded = 40)
  float* out = (float*)d_out;

  float* ws = (float*)d_ws;
  const size_t NQ = (size_t)B_ * H_ * L_ * DH_;  // 4194304
  float* Q      = ws;
  float* Kt     = Q + NQ;
  float* Vt     = Kt + NQ;
  float* ctx    = Vt + NQ;                       // B*L*D = 4194304
  float* Mv     = ctx + NQ;                      // 65536
  float* ctxUpd = Mv + (size_t)B_ * H_ * L_;     // 81920
  float* vmean  = ctxUpd + (size_t)B_ * H_ * U_ * DH_;  // 2048
  int*   topIdx = (int*)(vmean + B_ * H_ * DH_);        // 1280

  dim3 blk(256);
  gemm_qkv<<<dim3(3 * D_ / BN, B_ * L_ / BM), blk, 0, stream>>>(
      x, Wq, bq, Wkv, bkv, Q, Kt, Vt);
  sample_m<<<dim3(B_ * H_ * L_), dim3(64), 0, stream>>>(Q, Kt, idx, Mv);
  topk_kernel<<<dim3(B_ * H_), blk, 0, stream>>>(Mv, topIdx);
  attn_topq<<<dim3(B_ * H_ * U_), blk, 0, stream>>>(Q, Kt, Vt, topIdx, ctxUpd);
  vmean_kernel<<<dim3(B_ * H_), blk, 0, stream>>>(Vt, vmean);
  fill_context<<<dim3(B_ * L_ * D_ / 256), blk, 0, stream>>>(vmean, ctx);
  scatter_ctx<<<dim3(B_ * H_ * U_), dim3(64), 0, stream>>>(topIdx, ctxUpd, ctx);
  gemm_xwT<<<dim3(D_ / BN, B_ * L_ / BM), blk, 0, stream>>>(
      ctx, Wout, bout, out, B_ * L_, D_, D_);
}

// Round 2
// 697.615 us; speedup vs baseline: 1.6954x; 1.6954x over previous
//
#include <hip/hip_runtime.h>
#include <math.h>

// Problem constants (B=2, L=2048, D=1024, H=16, FACTOR=5)
#define B_ 2
#define L_ 2048
#define D_ 1024
#define H_ 16
#define DH_ 64
#define U_ 40
#define SCALE_ 0.125f

typedef __attribute__((ext_vector_type(8))) short short8v;   // 8 bf16 in 4 VGPRs
typedef __attribute__((ext_vector_type(4))) float f32x4;

static __device__ __forceinline__ unsigned short bf16_rne(float f) {
  unsigned int u = __float_as_uint(f);
  u += 0x7fff + ((u >> 16) & 1);
  return (unsigned short)(u >> 16);
}
static __device__ __forceinline__ float bf16_f32(unsigned short h) {
  return __uint_as_float(((unsigned int)h) << 16);
}

// ---------------------------------------------------------------------------
// Split-bf16 MFMA GEMM for QKV: C[m][n] = sum_k x[m][k] * W[n][k] + bias[n]
// M=4096, N=3072 (Q|K|V), K=1024. 128x128 tile, BK=32, 4 waves (2x2 of 64x64).
// Each f32 operand is decomposed on the fly into hi+lo bf16; 3 MFMAs per
// fragment pair give ~f32 accuracy (needed for the top-k selection cliff).
// LDS rows padded to 72 shorts (144B = 9*16B): b128 reads/writes conflict-free.
// ---------------------------------------------------------------------------
__global__ __launch_bounds__(256) void gemm_qkv_mfma(
    const float* __restrict__ X,
    const float* __restrict__ Wq, const float* __restrict__ bq,
    const float* __restrict__ Wkv, const float* __restrict__ bkv,
    float* __restrict__ Qo, float* __restrict__ Ko, float* __restrict__ Vo) {
  __shared__ unsigned short As[128][72];
  __shared__ unsigned short Bs[128][72];
  const int tid = threadIdx.x;
  const int lane = tid & 63;
  const int wave = tid >> 6;
  const int wm = wave >> 1, wn = wave & 1;
  const int row0 = blockIdx.y * 128;
  const int col0 = blockIdx.x * 128;

  f32x4 acc[4][4] = {};

  // Staging task decomposition: 512 (row, kgroup-of-8) tasks per operand,
  // thread handles tasks {tid, tid+256} for both A and B.
  const float* baseA[2];
  const float* baseB[2];
  unsigned short* ldsA_hi[2]; unsigned short* ldsA_lo[2];
  unsigned short* ldsB_hi[2]; unsigned short* ldsB_lo[2];
#pragma unroll
  for (int s = 0; s < 2; ++s) {
    int task = tid + s * 256;
    int r = task >> 2;     // 0..127
    int kg = task & 3;     // 0..3 (8 k's each)
    baseA[s] = X + (size_t)(row0 + r) * D_ + kg * 8;
    int n = col0 + r;
    baseB[s] = ((n < D_) ? (Wq + (size_t)n * D_)
                         : (Wkv + (size_t)(n - D_) * D_)) + kg * 8;
    ldsA_hi[s] = &As[r][kg * 8];
    ldsA_lo[s] = &As[r][32 + kg * 8];
    ldsB_hi[s] = &Bs[r][kg * 8];
    ldsB_lo[s] = &Bs[r][32 + kg * 8];
  }

  for (int k0 = 0; k0 < D_; k0 += 32) {
#pragma unroll
    for (int s = 0; s < 2; ++s) {
      float4 a0 = *(const float4*)(baseA[s] + k0);
      float4 a1 = *(const float4*)(baseA[s] + k0 + 4);
      float4 b0 = *(const float4*)(baseB[s] + k0);
      float4 b1 = *(const float4*)(baseB[s] + k0 + 4);
      float av[8] = {a0.x, a0.y, a0.z, a0.w, a1.x, a1.y, a1.z, a1.w};
      float bv[8] = {b0.x, b0.y, b0.z, b0.w, b1.x, b1.y, b1.z, b1.w};
      short8v ahi, alo, bhi, blo;
#pragma unroll
      for (int i = 0; i < 8; ++i) {
        unsigned short h = bf16_rne(av[i]);
        ahi[i] = (short)h;
        alo[i] = (short)bf16_rne(av[i] - bf16_f32(h));
        h = bf16_rne(bv[i]);
        bhi[i] = (short)h;
        blo[i] = (short)bf16_rne(bv[i] - bf16_f32(h));
      }
      *(short8v*)ldsA_hi[s] = ahi;
      *(short8v*)ldsA_lo[s] = alo;
      *(short8v*)ldsB_hi[s] = bhi;
      *(short8v*)ldsB_lo[s] = blo;
    }
    __syncthreads();

    short8v af[4][2], bf[4][2];
#pragma unroll
    for (int mi = 0; mi < 4; ++mi) {
      int rr = wm * 64 + mi * 16 + (lane & 15);
      int hs = lane >> 4;
      af[mi][0] = *(const short8v*)&As[rr][hs * 8];
      af[mi][1] = *(const short8v*)&As[rr][32 + hs * 8];
    }
#pragma unroll
    for (int ni = 0; ni < 4; ++ni) {
      int rr = wn * 64 + ni * 16 + (lane & 15);
      int hs = lane >> 4;
      bf[ni][0] = *(const short8v*)&Bs[rr][hs * 8];
      bf[ni][1] = *(const short8v*)&Bs[rr][32 + hs * 8];
    }
#pragma unroll
    for (int mi = 0; mi < 4; ++mi)
#pragma unroll
      for (int ni = 0; ni < 4; ++ni) {
        acc[mi][ni] = __builtin_amdgcn_mfma_f32_16x16x32_bf16(
            af[mi][0], bf[ni][0], acc[mi][ni], 0, 0, 0);
        acc[mi][ni] = __builtin_amdgcn_mfma_f32_16x16x32_bf16(
            af[mi][0], bf[ni][1], acc[mi][ni], 0, 0, 0);
        acc[mi][ni] = __builtin_amdgcn_mfma_f32_16x16x32_bf16(
            af[mi][1], bf[ni][0], acc[mi][ni], 0, 0, 0);
      }
    __syncthreads();
  }

  // Epilogue: C/D layout col=lane&15, row=(lane>>4)*4+reg.
#pragma unroll
  for (int ni = 0; ni < 4; ++ni) {
    int c = col0 + wn * 64 + ni * 16 + (lane & 15);
    int which = c >> 10;
    int jj = c & (D_ - 1);
    int h = jj >> 6, dh = jj & 63;
    float bias = (c < D_) ? bq[c] : bkv[c - D_];
    float* dst = (which == 0) ? Qo : ((which == 1) ? Ko : Vo);
#pragma unroll
    for (int mi = 0; mi < 4; ++mi) {
#pragma unroll
      for (int reg = 0; reg < 4; ++reg) {
        int r = row0 + wm * 64 + mi * 16 + ((lane >> 4) << 2) + reg;
        int b = r >> 11, l = r & (L_ - 1);
        dst[(((size_t)b * H_ + h) * L_ + l) * DH_ + dh] =
            acc[mi][ni][reg] + bias;
      }
    }
  }
}

// ---------------------------------------------------------------------------
// M[b,h,l] = max_u(QK) - mean_u(QK)
// ---------------------------------------------------------------------------
__global__ __launch_bounds__(64) void sample_m(
    const float* __restrict__ Q, const float* __restrict__ Kt,
    const int* __restrict__ idx, float* __restrict__ Mv) {
  int gl = blockIdx.x;
  int bh = gl >> 11, l = gl & (L_ - 1);
  __shared__ float qs[DH_];
  __shared__ float dots[U_];
  int t = threadIdx.x;
  qs[t] = Q[((size_t)bh * L_ + l) * DH_ + t];
  __syncthreads();
  if (t < U_) {
    int kl = idx[l * U_ + t];
    const float* kr = Kt + ((size_t)bh * L_ + kl) * DH_;
    float d = 0.f;
#pragma unroll
    for (int i = 0; i < DH_; ++i) d += qs[i] * kr[i];
    dots[t] = d;
  }
  __syncthreads();
  if (t == 0) {
    float mx = dots[0], sm = 0.f;
    for (int u = 0; u < U_; ++u) { mx = fmaxf(mx, dots[u]); sm += dots[u]; }
    Mv[gl] = mx - sm * (1.0f / U_);
  }
}

// ---------------------------------------------------------------------------
// Per-(b,h) top-U_ indices of M (iterative argmax, min-index tie-break).
// ---------------------------------------------------------------------------
__global__ __launch_bounds__(256) void topk_kernel(
    const float* __restrict__ Mv, int* __restrict__ topIdx) {
  int bh = blockIdx.x;
  __shared__ float vals[L_];
  __shared__ float rv[256];
  __shared__ int ri[256];
  int t = threadIdx.x;
  for (int i = t; i < L_; i += 256) vals[i] = Mv[(size_t)bh * L_ + i];
  __syncthreads();
  for (int it = 0; it < U_; ++it) {
    float bv = -INFINITY; int bi = 0x7fffffff;
    for (int i = t; i < L_; i += 256) {
      float v = vals[i];
      if (v > bv) { bv = v; bi = i; }
    }
    rv[t] = bv; ri[t] = bi;
    __syncthreads();
    for (int s = 128; s > 0; s >>= 1) {
      if (t < s) {
        float ov = rv[t + s]; int oi = ri[t + s];
        if (ov > rv[t] || (ov == rv[t] && oi < ri[t])) { rv[t] = ov; ri[t] = oi; }
      }
      __syncthreads();
    }
    if (t == 0) { topIdx[bh * U_ + it] = ri[0]; vals[ri[0]] = -INFINITY; }
    __syncthreads();
  }
}

// ---------------------------------------------------------------------------
// Full attention for the selected queries.
// ---------------------------------------------------------------------------
__global__ __launch_bounds__(256) void attn_topq(
    const float* __restrict__ Q, const float* __restrict__ Kt,
    const float* __restrict__ Vt, const int* __restrict__ topIdx,
    float* __restrict__ ctxUpd) {
  int bh = blockIdx.x / U_;
  int u  = blockIdx.x % U_;
  int ql = topIdx[bh * U_ + u];
  __shared__ float qs[DH_];
  __shared__ float sc[L_];
  __shared__ float red[256];
  int t = threadIdx.x;
  if (t < DH_) qs[t] = Q[((size_t)bh * L_ + ql) * DH_ + t];
  __syncthreads();
  float lmax = -INFINITY;
  for (int k = t; k < L_; k += 256) {
    const float* kr = Kt + ((size_t)bh * L_ + k) * DH_;
    float d = 0.f;
#pragma unroll
    for (int i = 0; i < DH_; ++i) d += qs[i] * kr[i];
    d *= SCALE_;
    sc[k] = d;
    lmax = fmaxf(lmax, d);
  }
  red[t] = lmax; __syncthreads();
  for (int s = 128; s > 0; s >>= 1) {
    if (t < s) red[t] = fmaxf(red[t], red[t + s]);
    __syncthreads();
  }
  float mx = red[0];
  __syncthreads();
  float lsum = 0.f;
  for (int k = t; k < L_; k += 256) {
    float e = expf(sc[k] - mx);
    sc[k] = e;
    lsum += e;
  }
  red[t] = lsum; __syncthreads();
  for (int s = 128; s > 0; s >>= 1) {
    if (t < s) red[t] += red[t + s];
    __syncthreads();
  }
  float inv = 1.0f / red[0];
  __syncthreads();
  int dh = t & 63, ch = t >> 6;
  float acc = 0.f;
  for (int k = ch * (L_ / 4); k < (ch + 1) * (L_ / 4); ++k)
    acc += sc[k] * Vt[((size_t)bh * L_ + k) * DH_ + dh];
  red[t] = acc; __syncthreads();
  if (ch == 0) {
    float r = (red[dh] + red[dh + 64]) + (red[dh + 128] + red[dh + 192]);
    ctxUpd[((size_t)bh * U_ + u) * DH_ + dh] = r * inv;
  }
}

// ---------------------------------------------------------------------------
// vmean[b,h,dh] = mean over l of V
// ---------------------------------------------------------------------------
__global__ __launch_bounds__(256) void vmean_kernel(
    const float* __restrict__ Vt, float* __restrict__ vmean) {
  int bh = blockIdx.x;
  int t = threadIdx.x;
  int dh = t & 63, ch = t >> 6;
  __shared__ float red[256];
  float s = 0.f;
  for (int l = ch * (L_ / 4); l < (ch + 1) * (L_ / 4); ++l)
    s += Vt[((size_t)bh * L_ + l) * DH_ + dh];
  red[t] = s; __syncthreads();
  if (ch == 0)
    vmean[bh * DH_ + dh] =
        ((red[dh] + red[dh + 64]) + (red[dh + 128] + red[dh + 192])) *
        (1.0f / L_);
}

// ---------------------------------------------------------------------------
// base[b][j] = vmean_flat[b] . Wout[j] + bout[j]   (vmean_flat = vmean[b,:,:])
// grid: B*16 blocks; block handles 64 j's with 4-way K-slicing.
// ---------------------------------------------------------------------------
__global__ __launch_bounds__(256) void base_kernel(
    const float* __restrict__ vmean, const float* __restrict__ Wout,
    const float* __restrict__ bout, float* __restrict__ baseOut) {
  int bid = blockIdx.x;
  int b = bid >> 4, jc = bid & 15;
  int t = threadIdx.x;
  int j = jc * 64 + (t & 63);
  int isl = t >> 6;
  __shared__ float vm[D_];
  __shared__ float red[256];
  for (int i = t; i < D_; i += 256) vm[i] = vmean[b * D_ + i];
  __syncthreads();
  float s = 0.f;
  const float* wr = Wout + (size_t)j * D_ + isl * 256;
  const float* vv = vm + isl * 256;
  for (int i = 0; i < 256; i += 4) {
    float4 w = *(const float4*)(wr + i);
    s += vv[i] * w.x + vv[i + 1] * w.y + vv[i + 2] * w.z + vv[i + 3] * w.w;
  }
  red[t] = s; __syncthreads();
  if (isl == 0)
    baseOut[b * D_ + j] =
        red[t] + red[t + 64] + red[t + 128] + red[t + 192] + bout[j];
}

// ---------------------------------------------------------------------------
// out[b,l,:] = base[b,:]  (float4 broadcast fill)
// ---------------------------------------------------------------------------
__global__ __launch_bounds__(256) void bcast_out(
    const float* __restrict__ baseIn, float* __restrict__ out) {
  size_t i4 = (size_t)blockIdx.x * 256 + threadIdx.x;  // over B*L*D/4
  size_t i = i4 * 4;
  int b = (int)(i >> 21);  // L_*D_ = 2^21
  int col = (int)(i & (D_ - 1));
  *(float4*)(out + i) = *(const float4*)(baseIn + b * D_ + col);
}

// ---------------------------------------------------------------------------
// out[b, l_u, :] += (ctxUpd[b,h,u] - vmean[b,h]) . Wout[:, h*64:(h+1)*64]^T
// ---------------------------------------------------------------------------
__global__ __launch_bounds__(256) void corr_kernel(
    const int* __restrict__ topIdx, const float* __restrict__ ctxUpd,
    const float* __restrict__ vmean, const float* __restrict__ Wout,
    float* __restrict__ out) {
  int bhu = blockIdx.x;
  int bh = bhu / U_;
  int h = bh & (H_ - 1), b = bh >> 4;
  int l = topIdx[bhu];
  __shared__ float dv[DH_];
  int t = threadIdx.x;
  if (t < DH_) dv[t] = ctxUpd[(size_t)bhu * DH_ + t] - vmean[bh * DH_ + t];
  __syncthreads();
  float* orow = out + ((size_t)b * L_ + l) * D_;
#pragma unroll
  for (int jj = 0; jj < 4; ++jj) {
    int j = jj * 256 + t;
    const float* wr = Wout + (size_t)j * D_ + h * DH_;
    float s = 0.f;
#pragma unroll
    for (int i = 0; i < DH_; i += 4) {
      float4 w = *(const float4*)(wr + i);
      s += dv[i] * w.x + dv[i + 1] * w.y + dv[i + 2] * w.z + dv[i + 3] * w.w;
    }
    atomicAdd(orow + j, s);
  }
}

// ---------------------------------------------------------------------------
extern "C" void kernel_launch(void* const* d_in, const int* in_sizes, int n_in,
                              void* d_out, int out_size, void* d_ws,
                              size_t ws_size, hipStream_t stream) {
  const float* x    = (const float*)d_in[0];
  const float* Wq   = (const float*)d_in[1];
  const float* bq   = (const float*)d_in[2];
  const float* Wkv  = (const float*)d_in[3];
  const float* bkv  = (const float*)d_in[4];
  const float* Wout = (const float*)d_in[5];
  const float* bout = (const float*)d_in[6];
  const int*   idx  = (const int*)d_in[7];
  float* out = (float*)d_out;

  float* ws = (float*)d_ws;
  const size_t NQ = (size_t)B_ * H_ * L_ * DH_;  // 4194304
  float* Q      = ws;
  float* Kt     = Q + NQ;
  float* Vt     = Kt + NQ;
  float* Mv     = Vt + NQ;                          // 65536
  float* ctxUpd = Mv + (size_t)B_ * H_ * L_;        // 81920
  float* vmean  = ctxUpd + (size_t)B_ * H_ * U_ * DH_;  // 2048
  float* baseB  = vmean + B_ * H_ * DH_;                // 2048
  int*   topIdx = (int*)(baseB + B_ * D_);              // 1280

  gemm_qkv_mfma<<<dim3(3 * D_ / 128, B_ * L_ / 128), dim3(256), 0, stream>>>(
      x, Wq, bq, Wkv, bkv, Q, Kt, Vt);
  sample_m<<<dim3(B_ * H_ * L_), dim3(64), 0, stream>>>(Q, Kt, idx, Mv);
  topk_kernel<<<dim3(B_ * H_), dim3(256), 0, stream>>>(Mv, topIdx);
  attn_topq<<<dim3(B_ * H_ * U_), dim3(256), 0, stream>>>(Q, Kt, Vt, topIdx,
                                                          ctxUpd);
  vmean_kernel<<<dim3(B_ * H_), dim3(256), 0, stream>>>(Vt, vmean);
  base_kernel<<<dim3(B_ * 16), dim3(256), 0, stream>>>(vmean, Wout, bout,
                                                       baseB);
  bcast_out<<<dim3(B_ * L_ * D_ / 1024), dim3(256), 0, stream>>>(baseB, out);
  corr_kernel<<<dim3(B_ * H_ * U_), dim3(256), 0, stream>>>(topIdx, ctxUpd,
                                                            vmean, Wout, out);
}

// Round 3
// 407.942 us; speedup vs baseline: 2.8993x; 1.7101x over previous
//
#include <hip/hip_runtime.h>
#include <math.h>

// Problem constants (B=2, L=2048, D=1024, H=16, FACTOR=5)
#define B_ 2
#define L_ 2048
#define D_ 1024
#define H_ 16
#define DH_ 64
#define U_ 40
#define SCALE_ 0.125f

typedef __attribute__((ext_vector_type(8))) short short8v;   // 8 bf16
typedef __attribute__((ext_vector_type(4))) float f32x4;

static __device__ __forceinline__ unsigned short bf16_rne(float f) {
  unsigned int u = __float_as_uint(f);
  u += 0x7fff + ((u >> 16) & 1);
  return (unsigned short)(u >> 16);
}
static __device__ __forceinline__ float bf16_f32(unsigned short h) {
  return __uint_as_float(((unsigned int)h) << 16);
}

// ---------------------------------------------------------------------------
// Split-bf16 MFMA GEMM for QKV (unchanged from round 2).
// ---------------------------------------------------------------------------
__global__ __launch_bounds__(256) void gemm_qkv_mfma(
    const float* __restrict__ X,
    const float* __restrict__ Wq, const float* __restrict__ bq,
    const float* __restrict__ Wkv, const float* __restrict__ bkv,
    float* __restrict__ Qo, float* __restrict__ Ko, float* __restrict__ Vo) {
  __shared__ unsigned short As[128][72];
  __shared__ unsigned short Bs[128][72];
  const int tid = threadIdx.x;
  const int lane = tid & 63;
  const int wave = tid >> 6;
  const int wm = wave >> 1, wn = wave & 1;
  const int row0 = blockIdx.y * 128;
  const int col0 = blockIdx.x * 128;

  f32x4 acc[4][4] = {};

  const float* baseA[2];
  const float* baseB[2];
  unsigned short* ldsA_hi[2]; unsigned short* ldsA_lo[2];
  unsigned short* ldsB_hi[2]; unsigned short* ldsB_lo[2];
#pragma unroll
  for (int s = 0; s < 2; ++s) {
    int task = tid + s * 256;
    int r = task >> 2;
    int kg = task & 3;
    baseA[s] = X + (size_t)(row0 + r) * D_ + kg * 8;
    int n = col0 + r;
    baseB[s] = ((n < D_) ? (Wq + (size_t)n * D_)
                         : (Wkv + (size_t)(n - D_) * D_)) + kg * 8;
    ldsA_hi[s] = &As[r][kg * 8];
    ldsA_lo[s] = &As[r][32 + kg * 8];
    ldsB_hi[s] = &Bs[r][kg * 8];
    ldsB_lo[s] = &Bs[r][32 + kg * 8];
  }

  for (int k0 = 0; k0 < D_; k0 += 32) {
#pragma unroll
    for (int s = 0; s < 2; ++s) {
      float4 a0 = *(const float4*)(baseA[s] + k0);
      float4 a1 = *(const float4*)(baseA[s] + k0 + 4);
      float4 b0 = *(const float4*)(baseB[s] + k0);
      float4 b1 = *(const float4*)(baseB[s] + k0 + 4);
      float av[8] = {a0.x, a0.y, a0.z, a0.w, a1.x, a1.y, a1.z, a1.w};
      float bv[8] = {b0.x, b0.y, b0.z, b0.w, b1.x, b1.y, b1.z, b1.w};
      short8v ahi, alo, bhi, blo;
#pragma unroll
      for (int i = 0; i < 8; ++i) {
        unsigned short h = bf16_rne(av[i]);
        ahi[i] = (short)h;
        alo[i] = (short)bf16_rne(av[i] - bf16_f32(h));
        h = bf16_rne(bv[i]);
        bhi[i] = (short)h;
        blo[i] = (short)bf16_rne(bv[i] - bf16_f32(h));
      }
      *(short8v*)ldsA_hi[s] = ahi;
      *(short8v*)ldsA_lo[s] = alo;
      *(short8v*)ldsB_hi[s] = bhi;
      *(short8v*)ldsB_lo[s] = blo;
    }
    __syncthreads();

    short8v af[4][2], bf[4][2];
#pragma unroll
    for (int mi = 0; mi < 4; ++mi) {
      int rr = wm * 64 + mi * 16 + (lane & 15);
      int hs = lane >> 4;
      af[mi][0] = *(const short8v*)&As[rr][hs * 8];
      af[mi][1] = *(const short8v*)&As[rr][32 + hs * 8];
    }
#pragma unroll
    for (int ni = 0; ni < 4; ++ni) {
      int rr = wn * 64 + ni * 16 + (lane & 15);
      int hs = lane >> 4;
      bf[ni][0] = *(const short8v*)&Bs[rr][hs * 8];
      bf[ni][1] = *(const short8v*)&Bs[rr][32 + hs * 8];
    }
#pragma unroll
    for (int mi = 0; mi < 4; ++mi)
#pragma unroll
      for (int ni = 0; ni < 4; ++ni) {
        acc[mi][ni] = __builtin_amdgcn_mfma_f32_16x16x32_bf16(
            af[mi][0], bf[ni][0], acc[mi][ni], 0, 0, 0);
        acc[mi][ni] = __builtin_amdgcn_mfma_f32_16x16x32_bf16(
            af[mi][0], bf[ni][1], acc[mi][ni], 0, 0, 0);
        acc[mi][ni] = __builtin_amdgcn_mfma_f32_16x16x32_bf16(
            af[mi][1], bf[ni][0], acc[mi][ni], 0, 0, 0);
      }
    __syncthreads();
  }

#pragma unroll
  for (int ni = 0; ni < 4; ++ni) {
    int c = col0 + wn * 64 + ni * 16 + (lane & 15);
    int which = c >> 10;
    int jj = c & (D_ - 1);
    int h = jj >> 6, dh = jj & 63;
    float bias = (c < D_) ? bq[c] : bkv[c - D_];
    float* dst = (which == 0) ? Qo : ((which == 1) ? Ko : Vo);
#pragma unroll
    for (int mi = 0; mi < 4; ++mi) {
#pragma unroll
      for (int reg = 0; reg < 4; ++reg) {
        int r = row0 + wm * 64 + mi * 16 + ((lane >> 4) << 2) + reg;
        int b = r >> 11, l = r & (L_ - 1);
        dst[(((size_t)b * H_ + h) * L_ + l) * DH_ + dh] =
            acc[mi][ni][reg] + bias;
      }
    }
  }
}

// ---------------------------------------------------------------------------
// M[b,h,l] = max_u(QK) - mean_u(QK). One wave per l, lane = u.
// ---------------------------------------------------------------------------
__global__ __launch_bounds__(256) void sample_m(
    const float* __restrict__ Q, const float* __restrict__ Kt,
    const int* __restrict__ idx, float* __restrict__ Mv) {
  int w = threadIdx.x >> 6, lane = threadIdx.x & 63;
  int gl = blockIdx.x * 4 + w;            // bh*L + l
  int bh = gl >> 11, l = gl & (L_ - 1);
  __shared__ float qs[4][DH_];
  qs[w][lane] = Q[((size_t)bh * L_ + l) * DH_ + lane];
  __syncthreads();
  float mx = -INFINITY, sm = 0.f;
  if (lane < U_) {
    int kl = idx[l * U_ + lane];
    const float* kr = Kt + ((size_t)bh * L_ + kl) * DH_;
    const float4* q4 = (const float4*)qs[w];
    float d = 0.f;
#pragma unroll
    for (int i4 = 0; i4 < 16; ++i4) {
      float4 k4 = *(const float4*)(kr + i4 * 4);
      float4 qv = q4[i4];
      d += k4.x * qv.x + k4.y * qv.y + k4.z * qv.z + k4.w * qv.w;
    }
    mx = d; sm = d;
  }
#pragma unroll
  for (int off = 1; off < 64; off <<= 1) {
    mx = fmaxf(mx, __shfl_xor(mx, off));
    sm += __shfl_xor(sm, off);
  }
  if (lane == 0) Mv[gl] = mx - sm * (1.0f / U_);
}

// ---------------------------------------------------------------------------
// Per-(b,h) top-U_ indices of M (iterative argmax, min-index tie-break).
// ---------------------------------------------------------------------------
__global__ __launch_bounds__(256) void topk_kernel(
    const float* __restrict__ Mv, int* __restrict__ topIdx) {
  int bh = blockIdx.x;
  __shared__ float vals[L_];
  __shared__ float rv[256];
  __shared__ int ri[256];
  int t = threadIdx.x;
  for (int i = t; i < L_; i += 256) vals[i] = Mv[(size_t)bh * L_ + i];
  __syncthreads();
  for (int it = 0; it < U_; ++it) {
    float bv = -INFINITY; int bi = 0x7fffffff;
    for (int i = t; i < L_; i += 256) {
      float v = vals[i];
      if (v > bv) { bv = v; bi = i; }
    }
    rv[t] = bv; ri[t] = bi;
    __syncthreads();
    for (int s = 128; s > 0; s >>= 1) {
      if (t < s) {
        float ov = rv[t + s]; int oi = ri[t + s];
        if (ov > rv[t] || (ov == rv[t] && oi < ri[t])) { rv[t] = ov; ri[t] = oi; }
      }
      __syncthreads();
    }
    if (t == 0) { topIdx[bh * U_ + it] = ri[0]; vals[ri[0]] = -INFINITY; }
    __syncthreads();
  }
}

// ---------------------------------------------------------------------------
// scores[bh][q][k] = scale * Qtop[q] . K[k]. Thread = one key, acc[40] regs.
// grid (kchunk=8, bh=32), 256 threads.
// ---------------------------------------------------------------------------
__global__ __launch_bounds__(256) void score_kernel(
    const float* __restrict__ Q, const float* __restrict__ Kt,
    const int* __restrict__ topIdx, float* __restrict__ S) {
  int kc = blockIdx.x, bh = blockIdx.y;
  int t = threadIdx.x;
  __shared__ float Qs[U_][DH_];
  for (int task = t; task < U_ * 16; task += 256) {
    int q = task >> 4, c4 = task & 15;
    int ql = topIdx[bh * U_ + q];
    *(float4*)&Qs[q][c4 * 4] =
        *(const float4*)&Q[((size_t)bh * L_ + ql) * DH_ + c4 * 4];
  }
  __syncthreads();

  const float* kr = Kt + ((size_t)bh * L_ + kc * 256 + t) * DH_;
  float acc[U_];
#pragma unroll
  for (int q = 0; q < U_; ++q) acc[q] = 0.f;

  float4 ka = *(const float4*)kr;
  for (int i4 = 0; i4 < 16; ++i4) {
    float4 kb = ka;
    if (i4 < 15) kb = *(const float4*)(kr + (i4 + 1) * 4);
#pragma unroll
    for (int q = 0; q < U_; ++q) {
      float4 qv = *(const float4*)&Qs[q][i4 * 4];
      acc[q] += ka.x * qv.x + ka.y * qv.y + ka.z * qv.z + ka.w * qv.w;
    }
    ka = kb;
  }
  float* srow = S + ((size_t)bh * U_) * L_ + kc * 256 + t;
#pragma unroll
  for (int q = 0; q < U_; ++q) srow[(size_t)q * L_] = acc[q] * SCALE_;
}

// ---------------------------------------------------------------------------
// Row softmax over S (in place). One block per row (bh*40 rows of 2048).
// ---------------------------------------------------------------------------
__global__ __launch_bounds__(256) void softmax_kernel(float* __restrict__ S) {
  float* r = S + (size_t)blockIdx.x * L_;
  int t = threadIdx.x;
  __shared__ float red[256];
  float v[8];
#pragma unroll
  for (int j = 0; j < 8; ++j) v[j] = r[t + j * 256];
  float mx = v[0];
#pragma unroll
  for (int j = 1; j < 8; ++j) mx = fmaxf(mx, v[j]);
  red[t] = mx; __syncthreads();
  for (int s = 128; s > 0; s >>= 1) {
    if (t < s) red[t] = fmaxf(red[t], red[t + s]);
    __syncthreads();
  }
  mx = red[0]; __syncthreads();
  float sm = 0.f;
#pragma unroll
  for (int j = 0; j < 8; ++j) { v[j] = __expf(v[j] - mx); sm += v[j]; }
  red[t] = sm; __syncthreads();
  for (int s = 128; s > 0; s >>= 1) {
    if (t < s) red[t] += red[t + s];
    __syncthreads();
  }
  float inv = 1.0f / red[0];
#pragma unroll
  for (int j = 0; j < 8; ++j) r[t + j * 256] = v[j] * inv;
}

// ---------------------------------------------------------------------------
// Partial PV: ctxPart[kc][bh][q][dh] = sum_{k in chunk} P[q][k] * V[k][dh].
// grid (kchunk=8, bh=32), 256 threads; wave owns 10 q-rows.
// ---------------------------------------------------------------------------
__global__ __launch_bounds__(256) void pv_kernel(
    const float* __restrict__ P, const float* __restrict__ Vt,
    float* __restrict__ ctxPart) {
  int kc = blockIdx.x, bh = blockIdx.y;
  int t = threadIdx.x;
  __shared__ float Ps[U_][256];
  for (int task = t; task < U_ * 64; task += 256) {
    int q = task >> 6, c4 = task & 63;
    *(float4*)&Ps[q][c4 * 4] =
        *(const float4*)&P[((size_t)(bh * U_ + q)) * L_ + kc * 256 + c4 * 4];
  }
  __syncthreads();
  int dh = t & 63, w = t >> 6;
  const float* vb = Vt + ((size_t)bh * L_ + kc * 256) * DH_ + dh;
  float acc[10];
#pragma unroll
  for (int j = 0; j < 10; ++j) acc[j] = 0.f;
  for (int k4 = 0; k4 < 64; ++k4) {
    float v0 = vb[(k4 * 4 + 0) * DH_];
    float v1 = vb[(k4 * 4 + 1) * DH_];
    float v2 = vb[(k4 * 4 + 2) * DH_];
    float v3 = vb[(k4 * 4 + 3) * DH_];
#pragma unroll
    for (int j = 0; j < 10; ++j) {
      float4 p4 = *(const float4*)&Ps[w + 4 * j][k4 * 4];
      acc[j] += p4.x * v0 + p4.y * v1 + p4.z * v2 + p4.w * v3;
    }
  }
#pragma unroll
  for (int j = 0; j < 10; ++j) {
    int q = w + 4 * j;
    ctxPart[(((size_t)kc * 32 + bh) * U_ + q) * DH_ + dh] = acc[j];
  }
}

// ---------------------------------------------------------------------------
// ctxUpd[bh][q][dh] = sum over 8 chunks of ctxPart.
// ---------------------------------------------------------------------------
__global__ __launch_bounds__(256) void merge_ctx(
    const float* __restrict__ ctxPart, float* __restrict__ ctxUpd) {
  int bh = blockIdx.x;
  int t = threadIdx.x;
  for (int e = t; e < U_ * DH_; e += 256) {
    float s = 0.f;
#pragma unroll
    for (int c = 0; c < 8; ++c)
      s += ctxPart[((size_t)c * 32 + bh) * (U_ * DH_) + e];
    ctxUpd[(size_t)bh * (U_ * DH_) + e] = s;
  }
}

// ---------------------------------------------------------------------------
// vmean partials: grid (chunk=8, bh=32).
// ---------------------------------------------------------------------------
__global__ __launch_bounds__(256) void vmean_part(
    const float* __restrict__ Vt, float* __restrict__ vmeanP) {
  int kc = blockIdx.x, bh = blockIdx.y;
  int t = threadIdx.x;
  int dh = t & 63, p = t >> 6;
  __shared__ float red[256];
  const float* vb = Vt + ((size_t)bh * L_ + kc * 256 + p * 64) * DH_ + dh;
  float s = 0.f;
  for (int j = 0; j < 64; ++j) s += vb[j * DH_];
  red[t] = s; __syncthreads();
  if (p == 0)
    vmeanP[(bh * 8 + kc) * DH_ + dh] =
        (red[dh] + red[dh + 64]) + (red[dh + 128] + red[dh + 192]);
}

__global__ __launch_bounds__(256) void vmean_merge(
    const float* __restrict__ vmeanP, float* __restrict__ vmean) {
  int e = blockIdx.x * 256 + threadIdx.x;  // over 32*64
  int bh = e >> 6, dh = e & 63;
  float s = 0.f;
#pragma unroll
  for (int kc = 0; kc < 8; ++kc) s += vmeanP[(bh * 8 + kc) * DH_ + dh];
  vmean[e] = s * (1.0f / L_);
}

// ---------------------------------------------------------------------------
// base[b][j] = vmean_flat[b] . Wout[j] + bout[j]
// ---------------------------------------------------------------------------
__global__ __launch_bounds__(256) void base_kernel(
    const float* __restrict__ vmean, const float* __restrict__ Wout,
    const float* __restrict__ bout, float* __restrict__ baseOut) {
  int bid = blockIdx.x;
  int b = bid >> 4, jc = bid & 15;
  int t = threadIdx.x;
  int j = jc * 64 + (t & 63);
  int isl = t >> 6;
  __shared__ float vm[D_];
  __shared__ float red[256];
  for (int i = t; i < D_; i += 256) vm[i] = vmean[b * D_ + i];
  __syncthreads();
  float s = 0.f;
  const float* wr = Wout + (size_t)j * D_ + isl * 256;
  const float* vv = vm + isl * 256;
  for (int i = 0; i < 256; i += 4) {
    float4 w = *(const float4*)(wr + i);
    s += vv[i] * w.x + vv[i + 1] * w.y + vv[i + 2] * w.z + vv[i + 3] * w.w;
  }
  red[t] = s; __syncthreads();
  if (isl == 0)
    baseOut[b * D_ + j] =
        red[t] + red[t + 64] + red[t + 128] + red[t + 192] + bout[j];
}

// ---------------------------------------------------------------------------
// out[b,l,:] = base[b,:]
// ---------------------------------------------------------------------------
__global__ __launch_bounds__(256) void bcast_out(
    const float* __restrict__ baseIn, float* __restrict__ out) {
  size_t i4 = (size_t)blockIdx.x * 256 + threadIdx.x;
  size_t i = i4 * 4;
  int b = (int)(i >> 21);
  int col = (int)(i & (D_ - 1));
  *(float4*)(out + i) = *(const float4*)(baseIn + b * D_ + col);
}

// ---------------------------------------------------------------------------
// out[b, l_u, :] += (ctxUpd[b,h,u] - vmean[b,h]) . Wout[:, h*64:(h+1)*64]^T
// ---------------------------------------------------------------------------
__global__ __launch_bounds__(256) void corr_kernel(
    const int* __restrict__ topIdx, const float* __restrict__ ctxUpd,
    const float* __restrict__ vmean, const float* __restrict__ Wout,
    float* __restrict__ out) {
  int bhu = blockIdx.x;
  int bh = bhu / U_;
  int h = bh & (H_ - 1), b = bh >> 4;
  int l = topIdx[bhu];
  __shared__ float dv[DH_];
  int t = threadIdx.x;
  if (t < DH_) dv[t] = ctxUpd[(size_t)bhu * DH_ + t] - vmean[bh * DH_ + t];
  __syncthreads();
  float* orow = out + ((size_t)b * L_ + l) * D_;
#pragma unroll
  for (int jj = 0; jj < 4; ++jj) {
    int j = jj * 256 + t;
    const float* wr = Wout + (size_t)j * D_ + h * DH_;
    float s = 0.f;
#pragma unroll
    for (int i = 0; i < DH_; i += 4) {
      float4 w = *(const float4*)(wr + i);
      s += dv[i] * w.x + dv[i + 1] * w.y + dv[i + 2] * w.z + dv[i + 3] * w.w;
    }
    atomicAdd(orow + j, s);
  }
}

// ---------------------------------------------------------------------------
extern "C" void kernel_launch(void* const* d_in, const int* in_sizes, int n_in,
                              void* d_out, int out_size, void* d_ws,
                              size_t ws_size, hipStream_t stream) {
  const float* x    = (const float*)d_in[0];
  const float* Wq   = (const float*)d_in[1];
  const float* bq   = (const float*)d_in[2];
  const float* Wkv  = (const float*)d_in[3];
  const float* bkv  = (const float*)d_in[4];
  const float* Wout = (const float*)d_in[5];
  const float* bout = (const float*)d_in[6];
  const int*   idx  = (const int*)d_in[7];
  float* out = (float*)d_out;

  float* ws = (float*)d_ws;
  const size_t NQ = (size_t)B_ * H_ * L_ * DH_;          // 4,194,304
  float* Q       = ws;
  float* Kt      = Q + NQ;
  float* Vt      = Kt + NQ;
  float* S       = Vt + NQ;                              // 32*40*2048
  float* Mv      = S + (size_t)32 * U_ * L_;             // 65,536
  float* ctxPart = Mv + (size_t)B_ * H_ * L_;            // 8*32*40*64
  float* ctxUpd  = ctxPart + (size_t)8 * 32 * U_ * DH_;  // 81,920
  float* vmeanP  = ctxUpd + (size_t)32 * U_ * DH_;       // 16,384
  float* vmean   = vmeanP + 32 * 8 * DH_;                // 2,048
  float* baseB   = vmean + 32 * DH_;                     // 2,048
  int*   topIdx  = (int*)(baseB + B_ * D_);              // 1,280

  gemm_qkv_mfma<<<dim3(3 * D_ / 128, B_ * L_ / 128), dim3(256), 0, stream>>>(
      x, Wq, bq, Wkv, bkv, Q, Kt, Vt);
  sample_m<<<dim3(B_ * H_ * L_ / 4), dim3(256), 0, stream>>>(Q, Kt, idx, Mv);
  topk_kernel<<<dim3(B_ * H_), dim3(256), 0, stream>>>(Mv, topIdx);
  score_kernel<<<dim3(8, 32), dim3(256), 0, stream>>>(Q, Kt, topIdx, S);
  softmax_kernel<<<dim3(32 * U_), dim3(256), 0, stream>>>(S);
  pv_kernel<<<dim3(8, 32), dim3(256), 0, stream>>>(S, Vt, ctxPart);
  merge_ctx<<<dim3(32), dim3(256), 0, stream>>>(ctxPart, ctxUpd);
  vmean_part<<<dim3(8, 32), dim3(256), 0, stream>>>(Vt, vmeanP);
  vmean_merge<<<dim3(8), dim3(256), 0, stream>>>(vmeanP, vmean);
  base_kernel<<<dim3(B_ * 16), dim3(256), 0, stream>>>(vmean, Wout, bout,
                                                       baseB);
  bcast_out<<<dim3(B_ * L_ * D_ / 1024), dim3(256), 0, stream>>>(baseB, out);
  corr_kernel<<<dim3(B_ * H_ * U_), dim3(256), 0, stream>>>(topIdx, ctxUpd,
                                                            vmean, Wout, out);
}

// Round 4
// 365.420 us; speedup vs baseline: 3.2367x; 1.1164x over previous
//
#include <hip/hip_runtime.h>
#include <math.h>

// Problem constants (B=2, L=2048, D=1024, H=16, FACTOR=5)
#define B_ 2
#define L_ 2048
#define D_ 1024
#define H_ 16
#define DH_ 64
#define U_ 40
#define SCALE_ 0.125f

typedef __attribute__((ext_vector_type(8))) short short8v;            // 8 bf16
typedef __attribute__((ext_vector_type(4))) float f32x4;
typedef __attribute__((ext_vector_type(4))) unsigned short ushort4v;  // 8 B

static __device__ __forceinline__ unsigned short bf16_rne(float f) {
  unsigned int u = __float_as_uint(f);
  u += 0x7fff + ((u >> 16) & 1);
  return (unsigned short)(u >> 16);
}
static __device__ __forceinline__ float bf16_f32(unsigned short h) {
  return __uint_as_float(((unsigned int)h) << 16);
}

// ---------------------------------------------------------------------------
// Pre-split: f32 -> (hi, lo) bf16 pair. W = [Wq; Wkv] rows concatenated.
// ---------------------------------------------------------------------------
__global__ __launch_bounds__(256) void split_w(
    const float* __restrict__ Wq, const float* __restrict__ Wkv,
    unsigned short* __restrict__ hi, unsigned short* __restrict__ lo) {
  int i = blockIdx.x * 256 + threadIdx.x;  // over 786432 float4 quads
  const int nq_q = (D_ * D_) / 4;          // 262144 quads of Wq
  float4 v = (i < nq_q) ? ((const float4*)Wq)[i]
                        : ((const float4*)Wkv)[i - nq_q];
  float vv[4] = {v.x, v.y, v.z, v.w};
  ushort4v h, l;
#pragma unroll
  for (int e = 0; e < 4; ++e) {
    unsigned short hh = bf16_rne(vv[e]);
    h[e] = hh;
    l[e] = bf16_rne(vv[e] - bf16_f32(hh));
  }
  ((ushort4v*)hi)[i] = h;
  ((ushort4v*)lo)[i] = l;
}

__global__ __launch_bounds__(256) void split_x(
    const float* __restrict__ X, unsigned short* __restrict__ hi,
    unsigned short* __restrict__ lo) {
  int i = blockIdx.x * 256 + threadIdx.x;  // over 1048576 quads
  float4 v = ((const float4*)X)[i];
  float vv[4] = {v.x, v.y, v.z, v.w};
  ushort4v h, l;
#pragma unroll
  for (int e = 0; e < 4; ++e) {
    unsigned short hh = bf16_rne(vv[e]);
    h[e] = hh;
    l[e] = bf16_rne(vv[e] - bf16_f32(hh));
  }
  ((ushort4v*)hi)[i] = h;
  ((ushort4v*)lo)[i] = l;
}

// ---------------------------------------------------------------------------
// Split-bf16 MFMA GEMM for QKV: C = X @ W^T + bias, M=4096 N=3072 K=1024.
// 128x128 tile, BK=32, 4 waves. hi/lo bf16 operands, 3 MFMAs per frag pair.
// XS: A pre-split in global; else A converted inline from f32.
// LDS rows padded to 72 shorts (144 B = 9*16 B): b128 ops conflict-free.
// ---------------------------------------------------------------------------
template <bool XS>
__global__ __launch_bounds__(256) void gemm_qkv_mfma(
    const float* __restrict__ X,
    const unsigned short* __restrict__ Xhi,
    const unsigned short* __restrict__ Xlo,
    const unsigned short* __restrict__ Whi,
    const unsigned short* __restrict__ Wlo,
    const float* __restrict__ bq, const float* __restrict__ bkv,
    float* __restrict__ Qo, float* __restrict__ Ko, float* __restrict__ Vo) {
  __shared__ unsigned short As[128][72];
  __shared__ unsigned short Bs[128][72];
  const int tid = threadIdx.x;
  const int lane = tid & 63;
  const int wave = tid >> 6;
  const int wm = wave >> 1, wn = wave & 1;
  const int row0 = blockIdx.y * 128;
  const int col0 = blockIdx.x * 128;

  f32x4 acc[4][4] = {};

  const float* srcAf[2];
  const unsigned short* srcAh[2];
  const unsigned short* srcAl[2];
  const unsigned short* srcBh[2];
  const unsigned short* srcBl[2];
  unsigned short* dA0[2]; unsigned short* dA1[2];
  unsigned short* dB0[2]; unsigned short* dB1[2];
#pragma unroll
  for (int s = 0; s < 2; ++s) {
    int task = tid + s * 256;
    int r = task >> 2;
    int kg = task & 3;
    size_t aoff = (size_t)(row0 + r) * D_ + kg * 8;
    if (XS) { srcAh[s] = Xhi + aoff; srcAl[s] = Xlo + aoff; srcAf[s] = 0; }
    else { srcAf[s] = X + aoff; srcAh[s] = 0; srcAl[s] = 0; }
    size_t boff = (size_t)(col0 + r) * D_ + kg * 8;
    srcBh[s] = Whi + boff;
    srcBl[s] = Wlo + boff;
    dA0[s] = &As[r][kg * 8];
    dA1[s] = &As[r][32 + kg * 8];
    dB0[s] = &Bs[r][kg * 8];
    dB1[s] = &Bs[r][32 + kg * 8];
  }

  for (int k0 = 0; k0 < D_; k0 += 32) {
#pragma unroll
    for (int s = 0; s < 2; ++s) {
      short8v ah, al;
      if (XS) {
        ah = *(const short8v*)(srcAh[s] + k0);
        al = *(const short8v*)(srcAl[s] + k0);
      } else {
        float4 a0 = *(const float4*)(srcAf[s] + k0);
        float4 a1 = *(const float4*)(srcAf[s] + k0 + 4);
        float av[8] = {a0.x, a0.y, a0.z, a0.w, a1.x, a1.y, a1.z, a1.w};
#pragma unroll
        for (int i = 0; i < 8; ++i) {
          unsigned short h = bf16_rne(av[i]);
          ah[i] = (short)h;
          al[i] = (short)bf16_rne(av[i] - bf16_f32(h));
        }
      }
      short8v bh = *(const short8v*)(srcBh[s] + k0);
      short8v bl = *(const short8v*)(srcBl[s] + k0);
      *(short8v*)dA0[s] = ah;
      *(short8v*)dA1[s] = al;
      *(short8v*)dB0[s] = bh;
      *(short8v*)dB1[s] = bl;
    }
    __syncthreads();

    short8v af[4][2], bf[4][2];
#pragma unroll
    for (int mi = 0; mi < 4; ++mi) {
      int rr = wm * 64 + mi * 16 + (lane & 15);
      int hs = lane >> 4;
      af[mi][0] = *(const short8v*)&As[rr][hs * 8];
      af[mi][1] = *(const short8v*)&As[rr][32 + hs * 8];
    }
#pragma unroll
    for (int ni = 0; ni < 4; ++ni) {
      int rr = wn * 64 + ni * 16 + (lane & 15);
      int hs = lane >> 4;
      bf[ni][0] = *(const short8v*)&Bs[rr][hs * 8];
      bf[ni][1] = *(const short8v*)&Bs[rr][32 + hs * 8];
    }
#pragma unroll
    for (int mi = 0; mi < 4; ++mi)
#pragma unroll
      for (int ni = 0; ni < 4; ++ni) {
        acc[mi][ni] = __builtin_amdgcn_mfma_f32_16x16x32_bf16(
            af[mi][0], bf[ni][0], acc[mi][ni], 0, 0, 0);
        acc[mi][ni] = __builtin_amdgcn_mfma_f32_16x16x32_bf16(
            af[mi][0], bf[ni][1], acc[mi][ni], 0, 0, 0);
        acc[mi][ni] = __builtin_amdgcn_mfma_f32_16x16x32_bf16(
            af[mi][1], bf[ni][0], acc[mi][ni], 0, 0, 0);
      }
    __syncthreads();
  }

  // Epilogue: C/D layout col=lane&15, row=(lane>>4)*4+reg.
#pragma unroll
  for (int ni = 0; ni < 4; ++ni) {
    int c = col0 + wn * 64 + ni * 16 + (lane & 15);
    int which = c >> 10;
    int jj = c & (D_ - 1);
    int h = jj >> 6, dh = jj & 63;
    float bias = (c < D_) ? bq[c] : bkv[c - D_];
    float* dst = (which == 0) ? Qo : ((which == 1) ? Ko : Vo);
#pragma unroll
    for (int mi = 0; mi < 4; ++mi) {
#pragma unroll
      for (int reg = 0; reg < 4; ++reg) {
        int r = row0 + wm * 64 + mi * 16 + ((lane >> 4) << 2) + reg;
        int b = r >> 11, l = r & (L_ - 1);
        dst[(((size_t)b * H_ + h) * L_ + l) * DH_ + dh] =
            acc[mi][ni][reg] + bias;
      }
    }
  }
}

// ---------------------------------------------------------------------------
// M[b,h,l] = max_u(QK) - mean_u(QK). One wave per l, lane = u.
// ---------------------------------------------------------------------------
__global__ __launch_bounds__(256) void sample_m(
    const float* __restrict__ Q, const float* __restrict__ Kt,
    const int* __restrict__ idx, float* __restrict__ Mv) {
  int w = threadIdx.x >> 6, lane = threadIdx.x & 63;
  int gl = blockIdx.x * 4 + w;  // bh*L + l
  int bh = gl >> 11, l = gl & (L_ - 1);
  __shared__ float qs[4][DH_];
  qs[w][lane] = Q[((size_t)bh * L_ + l) * DH_ + lane];
  __syncthreads();
  float mx = -INFINITY, sm = 0.f;
  if (lane < U_) {
    int kl = idx[l * U_ + lane];
    const float* kr = Kt + ((size_t)bh * L_ + kl) * DH_;
    const float4* q4 = (const float4*)qs[w];
    float d = 0.f;
#pragma unroll
    for (int i4 = 0; i4 < 16; ++i4) {
      float4 k4 = *(const float4*)(kr + i4 * 4);
      float4 qv = q4[i4];
      d += k4.x * qv.x + k4.y * qv.y + k4.z * qv.z + k4.w * qv.w;
    }
    mx = d; sm = d;
  }
#pragma unroll
  for (int off = 1; off < 64; off <<= 1) {
    mx = fmaxf(mx, __shfl_xor(mx, off));
    sm += __shfl_xor(sm, off);
  }
  if (lane == 0) Mv[gl] = mx - sm * (1.0f / U_);
}

// ---------------------------------------------------------------------------
// Per-(b,h) top-U_ indices of M (iterative argmax, min-index tie-break).
// ---------------------------------------------------------------------------
__global__ __launch_bounds__(256) void topk_kernel(
    const float* __restrict__ Mv, int* __restrict__ topIdx) {
  int bh = blockIdx.x;
  __shared__ float vals[L_];
  __shared__ float rv[256];
  __shared__ int ri[256];
  int t = threadIdx.x;
  for (int i = t; i < L_; i += 256) vals[i] = Mv[(size_t)bh * L_ + i];
  __syncthreads();
  for (int it = 0; it < U_; ++it) {
    float bv = -INFINITY; int bi = 0x7fffffff;
    for (int i = t; i < L_; i += 256) {
      float v = vals[i];
      if (v > bv) { bv = v; bi = i; }
    }
    rv[t] = bv; ri[t] = bi;
    __syncthreads();
    for (int s = 128; s > 0; s >>= 1) {
      if (t < s) {
        float ov = rv[t + s]; int oi = ri[t + s];
        if (ov > rv[t] || (ov == rv[t] && oi < ri[t])) { rv[t] = ov; ri[t] = oi; }
      }
      __syncthreads();
    }
    if (t == 0) { topIdx[bh * U_ + it] = ri[0]; vals[ri[0]] = -INFINITY; }
    __syncthreads();
  }
}

// ---------------------------------------------------------------------------
// scores[bh][q][k] = scale * Qtop[q] . K[k]. Thread = one key, acc[40] regs.
// ---------------------------------------------------------------------------
__global__ __launch_bounds__(256) void score_kernel(
    const float* __restrict__ Q, const float* __restrict__ Kt,
    const int* __restrict__ topIdx, float* __restrict__ S) {
  int kc = blockIdx.x, bh = blockIdx.y;
  int t = threadIdx.x;
  __shared__ float Qs[U_][DH_];
  for (int task = t; task < U_ * 16; task += 256) {
    int q = task >> 4, c4 = task & 15;
    int ql = topIdx[bh * U_ + q];
    *(float4*)&Qs[q][c4 * 4] =
        *(const float4*)&Q[((size_t)bh * L_ + ql) * DH_ + c4 * 4];
  }
  __syncthreads();

  const float* kr = Kt + ((size_t)bh * L_ + kc * 256 + t) * DH_;
  float acc[U_];
#pragma unroll
  for (int q = 0; q < U_; ++q) acc[q] = 0.f;

  float4 ka = *(const float4*)kr;
  for (int i4 = 0; i4 < 16; ++i4) {
    float4 kb = ka;
    if (i4 < 15) kb = *(const float4*)(kr + (i4 + 1) * 4);
#pragma unroll
    for (int q = 0; q < U_; ++q) {
      float4 qv = *(const float4*)&Qs[q][i4 * 4];
      acc[q] += ka.x * qv.x + ka.y * qv.y + ka.z * qv.z + ka.w * qv.w;
    }
    ka = kb;
  }
  float* srow = S + ((size_t)bh * U_) * L_ + kc * 256 + t;
#pragma unroll
  for (int q = 0; q < U_; ++q) srow[(size_t)q * L_] = acc[q] * SCALE_;
}

// ---------------------------------------------------------------------------
// Row softmax over S (in place). One block per row.
// ---------------------------------------------------------------------------
__global__ __launch_bounds__(256) void softmax_kernel(float* __restrict__ S) {
  float* r = S + (size_t)blockIdx.x * L_;
  int t = threadIdx.x;
  __shared__ float red[256];
  float v[8];
#pragma unroll
  for (int j = 0; j < 8; ++j) v[j] = r[t + j * 256];
  float mx = v[0];
#pragma unroll
  for (int j = 1; j < 8; ++j) mx = fmaxf(mx, v[j]);
  red[t] = mx; __syncthreads();
  for (int s = 128; s > 0; s >>= 1) {
    if (t < s) red[t] = fmaxf(red[t], red[t + s]);
    __syncthreads();
  }
  mx = red[0]; __syncthreads();
  float sm = 0.f;
#pragma unroll
  for (int j = 0; j < 8; ++j) { v[j] = __expf(v[j] - mx); sm += v[j]; }
  red[t] = sm; __syncthreads();
  for (int s = 128; s > 0; s >>= 1) {
    if (t < s) red[t] += red[t + s];
    __syncthreads();
  }
  float inv = 1.0f / red[0];
#pragma unroll
  for (int j = 0; j < 8; ++j) r[t + j * 256] = v[j] * inv;
}

// ---------------------------------------------------------------------------
// Partial PV (+ fused vmean partials): grid (kchunk=8, bh=32).
// ---------------------------------------------------------------------------
__global__ __launch_bounds__(256) void pv_kernel(
    const float* __restrict__ P, const float* __restrict__ Vt,
    float* __restrict__ ctxPart, float* __restrict__ vmeanP) {
  int kc = blockIdx.x, bh = blockIdx.y;
  int t = threadIdx.x;
  __shared__ float Ps[U_][256];
  for (int task = t; task < U_ * 64; task += 256) {
    int q = task >> 6, c4 = task & 63;
    *(float4*)&Ps[q][c4 * 4] =
        *(const float4*)&P[((size_t)(bh * U_ + q)) * L_ + kc * 256 + c4 * 4];
  }
  __syncthreads();
  int dh = t & 63, w = t >> 6;
  const float* vb = Vt + ((size_t)bh * L_ + kc * 256) * DH_ + dh;
  float acc[10];
#pragma unroll
  for (int j = 0; j < 10; ++j) acc[j] = 0.f;
  float vsum = 0.f;
  for (int k4 = 0; k4 < 64; ++k4) {
    float v0 = vb[(k4 * 4 + 0) * DH_];
    float v1 = vb[(k4 * 4 + 1) * DH_];
    float v2 = vb[(k4 * 4 + 2) * DH_];
    float v3 = vb[(k4 * 4 + 3) * DH_];
    vsum += (v0 + v1) + (v2 + v3);
#pragma unroll
    for (int j = 0; j < 10; ++j) {
      float4 p4 = *(const float4*)&Ps[w + 4 * j][k4 * 4];
      acc[j] += p4.x * v0 + p4.y * v1 + p4.z * v2 + p4.w * v3;
    }
  }
#pragma unroll
  for (int j = 0; j < 10; ++j) {
    int q = w + 4 * j;
    ctxPart[(((size_t)kc * 32 + bh) * U_ + q) * DH_ + dh] = acc[j];
  }
  if (w == 0) vmeanP[(bh * 8 + kc) * DH_ + dh] = vsum;
}

// ---------------------------------------------------------------------------
// ctxUpd[bh][q][dh] = sum over 8 chunks of ctxPart.
// ---------------------------------------------------------------------------
__global__ __launch_bounds__(256) void merge_ctx(
    const float* __restrict__ ctxPart, float* __restrict__ ctxUpd) {
  int bh = blockIdx.x;
  int t = threadIdx.x;
  for (int e = t; e < U_ * DH_; e += 256) {
    float s = 0.f;
#pragma unroll
    for (int c = 0; c < 8; ++c)
      s += ctxPart[((size_t)c * 32 + bh) * (U_ * DH_) + e];
    ctxUpd[(size_t)bh * (U_ * DH_) + e] = s;
  }
}

// ---------------------------------------------------------------------------
// base[b][j] = vmean_flat[b] . Wout[j] + bout[j]; vmean from partials.
// ---------------------------------------------------------------------------
__global__ __launch_bounds__(256) void base_kernel(
    const float* __restrict__ vmeanP, const float* __restrict__ Wout,
    const float* __restrict__ bout, float* __restrict__ baseOut) {
  int bid = blockIdx.x;
  int b = bid >> 4, jc = bid & 15;
  int t = threadIdx.x;
  int j = jc * 64 + (t & 63);
  int isl = t >> 6;
  __shared__ float vm[D_];
  __shared__ float red[256];
  for (int i = t; i < D_; i += 256) {
    int bh = b * H_ + (i >> 6), dh = i & 63;
    float s = 0.f;
#pragma unroll
    for (int kc = 0; kc < 8; ++kc) s += vmeanP[(bh * 8 + kc) * DH_ + dh];
    vm[i] = s * (1.0f / L_);
  }
  __syncthreads();
  float s = 0.f;
  const float* wr = Wout + (size_t)j * D_ + isl * 256;
  const float* vv = vm + isl * 256;
  for (int i = 0; i < 256; i += 4) {
    float4 w = *(const float4*)(wr + i);
    s += vv[i] * w.x + vv[i + 1] * w.y + vv[i + 2] * w.z + vv[i + 3] * w.w;
  }
  red[t] = s; __syncthreads();
  if (isl == 0)
    baseOut[b * D_ + j] =
        red[t] + red[t + 64] + red[t + 128] + red[t + 192] + bout[j];
}

// ---------------------------------------------------------------------------
// out[b,l,:] = base[b,:]
// ---------------------------------------------------------------------------
__global__ __launch_bounds__(256) void bcast_out(
    const float* __restrict__ baseIn, float* __restrict__ out) {
  size_t i4 = (size_t)blockIdx.x * 256 + threadIdx.x;
  size_t i = i4 * 4;
  int b = (int)(i >> 21);
  int col = (int)(i & (D_ - 1));
  *(float4*)(out + i) = *(const float4*)(baseIn + b * D_ + col);
}

// ---------------------------------------------------------------------------
// out[b, l_u, :] += (ctxUpd[b,h,u] - vmean[b,h]) . Wout[:, h*64:(h+1)*64]^T
// Coalesced: 4 lanes per output j (64 consecutive floats of Wout row).
// ---------------------------------------------------------------------------
__global__ __launch_bounds__(256) void corr_kernel(
    const int* __restrict__ topIdx, const float* __restrict__ ctxUpd,
    const float* __restrict__ vmeanP, const float* __restrict__ Wout,
    float* __restrict__ out) {
  int bhu = blockIdx.x;
  int bh = bhu / U_;
  int h = bh & (H_ - 1), b = bh >> 4;
  int l = topIdx[bhu];
  __shared__ float dv[DH_];
  int t = threadIdx.x;
  if (t < DH_) {
    float s = 0.f;
#pragma unroll
    for (int kc = 0; kc < 8; ++kc) s += vmeanP[(bh * 8 + kc) * DH_ + t];
    dv[t] = ctxUpd[(size_t)bhu * DH_ + t] - s * (1.0f / L_);
  }
  __syncthreads();
  int sub = t & 3;       // 16-float segment within the 64-col block
  int jbase = t >> 2;    // 0..63
  float* orow = out + ((size_t)b * L_ + l) * D_;
  const float* dvs = dv + sub * 16;
#pragma unroll
  for (int jc = 0; jc < 16; ++jc) {
    int j = jc * 64 + jbase;
    const float* wr = Wout + (size_t)j * D_ + h * DH_ + sub * 16;
    float s = 0.f;
#pragma unroll
    for (int i = 0; i < 16; i += 4) {
      float4 w = *(const float4*)(wr + i);
      s += dvs[i] * w.x + dvs[i + 1] * w.y + dvs[i + 2] * w.z +
           dvs[i + 3] * w.w;
    }
    s += __shfl_xor(s, 1);
    s += __shfl_xor(s, 2);
    if (sub == 0) atomicAdd(orow + j, s);
  }
}

// ---------------------------------------------------------------------------
extern "C" void kernel_launch(void* const* d_in, const int* in_sizes, int n_in,
                              void* d_out, int out_size, void* d_ws,
                              size_t ws_size, hipStream_t stream) {
  const float* x    = (const float*)d_in[0];
  const float* Wq   = (const float*)d_in[1];
  const float* bq   = (const float*)d_in[2];
  const float* Wkv  = (const float*)d_in[3];
  const float* bkv  = (const float*)d_in[4];
  const float* Wout = (const float*)d_in[5];
  const float* bout = (const float*)d_in[6];
  const int*   idx  = (const int*)d_in[7];
  float* out = (float*)d_out;

  float* ws = (float*)d_ws;
  const size_t NQ = (size_t)B_ * H_ * L_ * DH_;  // 4,194,304 floats
  float* Q  = ws;
  float* Kt = Q + NQ;
  float* Vt = Kt + NQ;
  // W/X split region (live only through the GEMM)
  unsigned short* Whi = (unsigned short*)(Vt + NQ);        // 6 MB
  unsigned short* Wlo = Whi + (size_t)3 * D_ * D_;         // 6 MB
  unsigned short* Xhi = Wlo + (size_t)3 * D_ * D_;         // 8 MB (optional)
  unsigned short* Xlo = Xhi + NQ;                          // 8 MB (optional)
  // phase-2 region (overlaps W/X split region; used only after the GEMM)
  float* S       = Vt + NQ;                                // 10 MB
  float* Mv      = S + (size_t)32 * U_ * L_;
  float* ctxPart = Mv + (size_t)B_ * H_ * L_;
  float* ctxUpd  = ctxPart + (size_t)8 * 32 * U_ * DH_;
  float* vmeanP  = ctxUpd + (size_t)32 * U_ * DH_;
  float* baseB   = vmeanP + 32 * 8 * DH_;
  int*   topIdx  = (int*)(baseB + B_ * D_);

  const bool xsplit = ws_size >= ((size_t)76 << 20);  // Xhi/Xlo fit?

  split_w<<<dim3(3 * D_ * D_ / 1024), dim3(256), 0, stream>>>(Wq, Wkv, Whi,
                                                              Wlo);
  if (xsplit) {
    split_x<<<dim3(NQ / 1024), dim3(256), 0, stream>>>(x, Xhi, Xlo);
    gemm_qkv_mfma<true>
        <<<dim3(3 * D_ / 128, B_ * L_ / 128), dim3(256), 0, stream>>>(
            x, Xhi, Xlo, Whi, Wlo, bq, bkv, Q, Kt, Vt);
  } else {
    gemm_qkv_mfma<false>
        <<<dim3(3 * D_ / 128, B_ * L_ / 128), dim3(256), 0, stream>>>(
            x, Xhi, Xlo, Whi, Wlo, bq, bkv, Q, Kt, Vt);
  }
  sample_m<<<dim3(B_ * H_ * L_ / 4), dim3(256), 0, stream>>>(Q, Kt, idx, Mv);
  topk_kernel<<<dim3(B_ * H_), dim3(256), 0, stream>>>(Mv, topIdx);
  score_kernel<<<dim3(8, 32), dim3(256), 0, stream>>>(Q, Kt, topIdx, S);
  softmax_kernel<<<dim3(32 * U_), dim3(256), 0, stream>>>(S);
  pv_kernel<<<dim3(8, 32), dim3(256), 0, stream>>>(S, Vt, ctxPart, vmeanP);
  merge_ctx<<<dim3(32), dim3(256), 0, stream>>>(ctxPart, ctxUpd);
  base_kernel<<<dim3(B_ * 16), dim3(256), 0, stream>>>(vmeanP, Wout, bout,
                                                       baseB);
  bcast_out<<<dim3(B_ * L_ * D_ / 1024), dim3(256), 0, stream>>>(baseB, out);
  corr_kernel<<<dim3(B_ * H_ * U_), dim3(256), 0, stream>>>(topIdx, ctxUpd,
                                                            vmeanP, Wout, out);
}